// Round 3
// baseline (51.980 us; speedup 1.0000x reference)
//
#include <hip/hip_runtime.h>
#include <math.h>

// BettingLoss: scalar loss over B=1048576 races, T=8 dogs.
// Inputs (float32, each B*T): predicted_probs, true_winners(one-hot),
// market_odds, gumbel_noise. Output: 1 float32 scalar.
//
// R2: coalescing fix. Old layout: thread r loaded float4 #2r,#2r+1 ->
// lane-stride 32B inside each load instr (16 lines/instr, 2x request rate,
// measured 3.2 TB/s = half of float4-stream ceiling, same speed L3 or HBM).
// New: 2 lanes cooperate per race; thread t loads float4 #t (lane-stride
// 16B, 8 lines/instr). Race-wide reductions via __shfl_xor(.,1) lane pairs.

constexpr int NT = 256;

__device__ __forceinline__ float fastrcp(float x) {
  return __builtin_amdgcn_rcpf(x);
}

// accumulator indices: 0=cnt, 1=sum(ce*valid), 2=sum(ce), 3=sum(soft_ep*valid),
// 4=sum(max_prob), 5=sum(entropy)
__global__ __launch_bounds__(NT, 4) void betting_main(
    const float4* __restrict__ pp4, const float4* __restrict__ tw4,
    const float4* __restrict__ mo4, const float4* __restrict__ gn4,
    float* __restrict__ partials, int nhalf) {
  const int tid = blockIdx.x * NT + threadIdx.x;
  const int ntot = gridDim.x * NT;  // even -> lane pairing preserved per iter

  float acc[6] = {0.f, 0.f, 0.f, 0.f, 0.f, 0.f};

  for (int f = tid; f < nhalf; f += ntot) {
    // Thread handles half-race f: race f>>1, dogs [4*(f&1), 4*(f&1)+4).
    // Partner half is in lane^1 (f^1 = same race, other half).
    float4 av = pp4[f];
    float4 wv = tw4[f];
    float4 ov = mo4[f];
    float4 gv = gn4[f];
    float p[4] = {av.x, av.y, av.z, av.w};
    float w[4] = {wv.x, wv.y, wv.z, wv.w};
    float o[4] = {ov.x, ov.y, ov.z, ov.w};
    float g[4] = {gv.x, gv.y, gv.z, gv.w};

    // ---- validity (race-wide via pair shuffles) ----
    float anyp = 0.f, simp = 0.f;
#pragma unroll
    for (int t = 0; t < 4; ++t) {
      anyp = fmaxf(anyp, (o[t] > 0.f) ? 1.f : 0.f);
      simp += fastrcp(fmaxf(o[t], 1.01f));
    }
    anyp = fmaxf(anyp, __shfl_xor(anyp, 1));
    simp = simp + __shfl_xor(simp, 1);
    float vf = (anyp > 0.5f && simp >= 0.95f) ? 1.f : 0.f;

    // ---- expected profit (masked by vf) ----
    float ep[4];
#pragma unroll
    for (int t = 0; t < 4; ++t)
      ep[t] = (o[t] * 1.1f * p[t] - 1.f) * (0.02f * 0.95f) * vf;

    // ---- gumbel-softmax selection: softmax(ep*100 + g*10) over 8 dogs ----
    float z[4], zmh = -INFINITY;
#pragma unroll
    for (int t = 0; t < 4; ++t) {
      z[t] = ep[t] * 100.f + g[t] * 10.f;
      zmh = fmaxf(zmh, z[t]);
    }
    float zm = fmaxf(zmh, __shfl_xor(zmh, 1));
    float s2h = 0.f, sph = 0.f;
#pragma unroll
    for (int t = 0; t < 4; ++t) {
      float e = __expf(z[t] - zm);
      s2h += e;
      sph += e * ep[t];
    }
    float s2 = s2h + __shfl_xor(s2h, 1);
    float sp = sph + __shfl_xor(sph, 1);
    float soft_ep = sp * fastrcp(s2);  // full-race value, same in both lanes

    // ---- cross-entropy: probs treated as logits ----
    float mh = fmaxf(fmaxf(p[0], p[1]), fmaxf(p[2], p[3]));
    float m = fmaxf(mh, __shfl_xor(mh, 1));
    float seh = 0.f, plh = 0.f;
#pragma unroll
    for (int t = 0; t < 4; ++t) {
      seh += __expf(p[t] - m);
      plh += w[t] * p[t];  // one-hot exact
    }
    float se = seh + __shfl_xor(seh, 1);
    // per-lane half-share of ce: pair-sum = m + log(se) - plabel_full
    float celin = 0.5f * (m + __logf(se)) - plh;

    // ---- entropy (linear, per-half) ----
    float enth = 0.f;
#pragma unroll
    for (int t = 0; t < 4; ++t) enth -= p[t] * __logf(p[t] + 1e-8f);

    acc[0] += 0.5f * vf;
    acc[1] += celin * vf;
    acc[2] += celin;
    acc[3] += 0.5f * soft_ep * vf;
    acc[4] += 0.5f * m;
    acc[5] += enth;
  }

  // ---- block reduction: wave shfl -> LDS -> partials ----
  __shared__ float red[NT / 64][6];
#pragma unroll
  for (int k = 0; k < 6; ++k) {
#pragma unroll
    for (int off = 32; off >= 1; off >>= 1) acc[k] += __shfl_down(acc[k], off);
  }
  int lane = threadIdx.x & 63, wave = threadIdx.x >> 6;
  if (lane == 0) {
#pragma unroll
    for (int k = 0; k < 6; ++k) red[wave][k] = acc[k];
  }
  __syncthreads();
  if (threadIdx.x == 0) {
#pragma unroll
    for (int k = 0; k < 6; ++k) {
      float s = 0.f;
      for (int wv = 0; wv < NT / 64; ++wv) s += red[wv][k];
      partials[k * gridDim.x + blockIdx.x] = s;  // SoA for coalesced finalize
    }
  }
}

__global__ __launch_bounds__(NT) void betting_final(
    const float* __restrict__ partials, int nb, float* __restrict__ out,
    double Bd) {
  __shared__ double red[NT / 64][6];
  double a[6] = {0, 0, 0, 0, 0, 0};
#pragma unroll
  for (int k = 0; k < 6; ++k)
    for (int i = threadIdx.x; i < nb; i += NT) a[k] += (double)partials[k * nb + i];
#pragma unroll
  for (int k = 0; k < 6; ++k) {
#pragma unroll
    for (int off = 32; off >= 1; off >>= 1) a[k] += __shfl_down(a[k], off);
  }
  int lane = threadIdx.x & 63, wave = threadIdx.x >> 6;
  if (lane == 0) {
#pragma unroll
    for (int k = 0; k < 6; ++k) red[wave][k] = a[k];
  }
  __syncthreads();
  if (threadIdx.x == 0) {
    double s[6];
#pragma unroll
    for (int k = 0; k < 6; ++k) {
      s[k] = 0.0;
      for (int wv = 0; wv < NT / 64; ++wv) s[k] += red[wv][k];
    }
    double cnt = s[0], Scev = s[1], Sce = s[2], Ssoft = s[3], Smax = s[4],
           Sent = s[5];
    double pred = (cnt > 0.0) ? Scev / fmax(cnt, 1.0) : Sce / Bd;
    double conf = -(Smax / Bd) * 0.1;
    double bet = (cnt > 0.0) ? -Ssoft / Bd : conf;
    double ent = Sent / Bd;
    double lam = fmin(0.5 + cnt / 10000.0 * 0.5, 1.0);
    out[0] = (float)(pred + lam * bet - 0.01 * ent);
  }
}

extern "C" void kernel_launch(void* const* d_in, const int* in_sizes, int n_in,
                              void* d_out, int out_size, void* d_ws,
                              size_t ws_size, hipStream_t stream) {
  const float4* pp = (const float4*)d_in[0];
  const float4* tw = (const float4*)d_in[1];
  const float4* mo = (const float4*)d_in[2];
  const float4* gn = (const float4*)d_in[3];
  float* out = (float*)d_out;
  float* partials = (float*)d_ws;

  int nraces = in_sizes[0] / 8;
  int nhalf = nraces * 2;  // float4 count per array

  // grid sized so the per-thread loop runs ~2 iterations; shrink if d_ws small
  int nb = 4096;
  while ((size_t)(6 * nb * 4) > ws_size && nb > 64) nb >>= 1;

  betting_main<<<nb, NT, 0, stream>>>(pp, tw, mo, gn, partials, nhalf);
  betting_final<<<1, NT, 0, stream>>>(partials, nb, out, (double)nraces);
}